// Round 3
// baseline (362.667 us; speedup 1.0000x reference)
//
#include <hip/hip_runtime.h>
#include <math.h>

#define F_NODES 16384
#define DEG 8
#define E_TOT (F_NODES * DEG)   // 131072
#define B 64
#define H 16
#define LAYERS 10

// ---------------------------------------------------------------------------
// Transpose x0 (B, E) -> x0T (E, B). Tiled through LDS, both sides coalesced.
// ---------------------------------------------------------------------------
__global__ __launch_bounds__(256) void transpose_in_kernel(
    const float* __restrict__ x0, float* __restrict__ xT)
{
    __shared__ float tile[64 * 65];
    const int e0 = blockIdx.x * 64;
    const int c  = threadIdx.x & 63;   // e offset within tile
    const int r  = threadIdx.x >> 6;   // 0..3

    #pragma unroll
    for (int i = 0; i < 16; ++i) {
        const int b = r + i * 4;
        tile[c * 65 + b] = x0[(size_t)b * E_TOT + e0 + c];
    }
    __syncthreads();
    const int b = threadIdx.x & 63;
    #pragma unroll
    for (int i = 0; i < 16; ++i) {
        const int el = r + i * 4;
        xT[(size_t)(e0 + el) * B + b] = tile[el * 65 + b];
    }
}

// inv[P[k]] = k  (P = flat in_ixs, a permutation of E)
__global__ __launch_bounds__(256) void build_inv_kernel(
    const int* __restrict__ in_ixs, int* __restrict__ inv)
{
    const int k = blockIdx.x * 256 + threadIdx.x;
    inv[in_ixs[k]] = k;
}

__device__ __forceinline__ float fast_elu(float x)
{
    float e = __builtin_amdgcn_exp2f(x * 1.44269504088896340736f) - 1.0f;
    return x > 0.0f ? x : e;
}

// ---------------------------------------------------------------------------
// One GSNN layer. One wave handles NPW nodes; lane = batch index b.
// Inter-layer activations are stored PRE-PERMUTED: z[k] = x[P[k]], so the
// per-node input read is sequential (2KB contiguous). The permutation is
// applied at the WRITE side via inv (scatter stores: latency-free).
//   SEQ_IN=false : g[d] = xin[P[f*8+d]*B+lane]   (random gather - layer 0)
//   SEQ_IN=true  : g[d] = xin[(f*8+d)*B+lane]    (sequential)
//   OUT_MODE=0   : z'[inv[f*8+d]*B+lane] = o[d]  (scatter, pre-permuted)
//   OUT_MODE=1   : out[(B,E) natural]            (final layer)
// Weights/biases/indices are wave-uniform -> s_load; FMAs use SGPR operand.
// ---------------------------------------------------------------------------
#define NPW 2   // nodes per wave

template <bool SEQ_IN, int OUT_MODE>
__global__ __launch_bounds__(256) void layer_kernel(
    const float* __restrict__ xin,    // (E, B) plain (layer0) or pre-permuted
    const float* __restrict__ x0T,    // (E, B) residual source
    const float* __restrict__ W1,     // (F, H, DEG)
    const float* __restrict__ b1,     // (F, H)
    const float* __restrict__ W2,     // (F, DEG, H)
    const float* __restrict__ b2,     // (F, DEG)
    const int*   __restrict__ in_ixs, // (F, DEG) = P
    const int*   __restrict__ inv,    // (E)      = P^-1
    float* __restrict__ xout)         // pre-permuted (E,B), or (B,E) if final
{
    const int lane    = threadIdx.x & 63;
    const int wv      = threadIdx.x >> 6;                // 0..3
    const int wave_id = (int)blockIdx.x * 4 + wv;        // 0..F/NPW-1

    #pragma unroll
    for (int n = 0; n < NPW; ++n) {
        const int f = __builtin_amdgcn_readfirstlane(wave_id * NPW + n);

        // input + residual loads (all issued up front)
        float g[DEG], r[DEG];
        const float* resp = x0T + (size_t)f * DEG * B + lane;
        if (SEQ_IN) {
            const float* inp = xin + (size_t)f * DEG * B + lane;
            #pragma unroll
            for (int d = 0; d < DEG; ++d) {
                g[d] = inp[d * B];
                r[d] = resp[d * B];
            }
        } else {
            const int* ixp = in_ixs + f * DEG;
            #pragma unroll
            for (int d = 0; d < DEG; ++d) {
                const int ix = ixp[d];
                g[d] = xin[(size_t)ix * B + lane];
                r[d] = resp[d * B];
            }
        }

        // h = elu(g @ W1^T + b1)
        const float* w1  = W1 + f * (H * DEG);
        const float* bb1 = b1 + f * H;
        float h[H];
        #pragma unroll
        for (int j = 0; j < H; ++j) {
            float acc = bb1[j];
            #pragma unroll
            for (int d = 0; d < DEG; ++d)
                acc = fmaf(w1[j * DEG + d], g[d], acc);
            h[j] = fast_elu(acc);
        }

        // o = h @ W2^T + b2 + residual(x0)
        const float* w2  = W2 + f * (DEG * H);
        const float* bb2 = b2 + f * DEG;
        float o[DEG];
        #pragma unroll
        for (int d = 0; d < DEG; ++d) {
            float acc = bb2[d];
            #pragma unroll
            for (int j = 0; j < H; ++j)
                acc = fmaf(w2[d * H + j], h[j], acc);
            o[d] = acc + r[d];
        }

        if (OUT_MODE == 1) {
            // final: write (B, E); lane b owns 8 consecutive floats at row b
            float4 v0 = make_float4(o[0], o[1], o[2], o[3]);
            float4 v1 = make_float4(o[4], o[5], o[6], o[7]);
            float4* dst = (float4*)(xout + (size_t)lane * E_TOT + f * DEG);
            dst[0] = v0;
            dst[1] = v1;
        } else {
            // scatter into pre-permuted layout for the next layer's seq read
            const int* invp = inv + f * DEG;   // wave-uniform s_loads
            #pragma unroll
            for (int d = 0; d < DEG; ++d) {
                const int k = invp[d];
                xout[(size_t)k * B + lane] = o[d];
            }
        }
    }
}

extern "C" void kernel_launch(void* const* d_in, const int* in_sizes, int n_in,
                              void* d_out, int out_size, void* d_ws, size_t ws_size,
                              hipStream_t stream)
{
    const float* x0     = (const float*)d_in[0];
    const float* W1     = (const float*)d_in[1];
    const float* b1     = (const float*)d_in[2];
    const float* W2     = (const float*)d_in[3];
    const float* b2     = (const float*)d_in[4];
    const int*   in_ixs = (const int*)d_in[5];
    float* out = (float*)d_out;

    const size_t NEL = (size_t)E_TOT * B;   // 8.39M floats = 32 MB
    float* buf0 = (float*)d_ws;             // x0T, kept for residuals
    float* buf1 = buf0 + NEL;               // z ping
    float* buf2 = buf1 + NEL;               // z pong
    int*   inv  = (int*)(buf2 + NEL);       // 512 KB inverse permutation

    transpose_in_kernel<<<E_TOT / 64, 256, 0, stream>>>(x0, buf0);
    build_inv_kernel<<<E_TOT / 256, 256, 0, stream>>>(in_ixs, inv);

    const int grid = F_NODES / (4 * NPW);

    // layer 0: gather from x0T, scatter-write pre-permuted z into buf1
    layer_kernel<false, 0><<<grid, 256, 0, stream>>>(
        buf0, buf0, W1, b1, W2, b2, in_ixs, inv, buf1);

    const float* cur = buf1;
    float* nxt = buf2;
    for (int l = 1; l < LAYERS - 1; ++l) {
        layer_kernel<true, 0><<<grid, 256, 0, stream>>>(
            cur, buf0, W1, b1, W2, b2, in_ixs, inv, nxt);
        cur = nxt;
        nxt = (cur == buf1) ? buf2 : buf1;
    }

    // final layer: sequential read, natural (B, E) write to d_out
    layer_kernel<true, 1><<<grid, 256, 0, stream>>>(
        cur, buf0, W1, b1, W2, b2, in_ixs, inv, out);
}